// Round 1
// baseline (84.310 us; speedup 1.0000x reference)
//
#include <hip/hip_runtime.h>

typedef float f32x4 __attribute__((ext_vector_type(4)));
typedef short short8 __attribute__((ext_vector_type(8)));

#define NTYPES 4

// ws layout (bytes):
//   [0,16)      counts[4]
//   [16,32)     cursors[4]
//   [32,52)     bases[5]        (meta ints: 0-3 counts, 4-7 cursors, 8-12 bases)
//   [1024, ...) perm[ntiles*64] ints (sentinel -1)
//   [402432,)   W1T bf16 [4][256][128]  (262144 B)
//   [664576,)   W2T bf16 [4][128][256]  (262144 B)

static __device__ __forceinline__ unsigned short f2bf(float f) {
  union { float f; unsigned int u; } v; v.f = f;
  unsigned int u = v.u;
  unsigned int r = u + 0x7FFFu + ((u >> 16) & 1u);   // round-nearest-even
  return (unsigned short)(r >> 16);
}

__global__ __launch_bounds__(256) void k_prep(const float* __restrict__ W1,
                                              const float* __restrict__ W2,
                                              unsigned short* __restrict__ W1T,
                                              unsigned short* __restrict__ W2T) {
  int i = blockIdx.x * 256 + threadIdx.x;   // 0..131071
  int t = i >> 15, rem = i & 32767;
  {
    int c = rem >> 7, k = rem & 127;        // W1T[t][c][k] = W1[t][k][c]
    W1T[i] = f2bf(W1[(t << 15) + k * 256 + c]);
  }
  {
    int o = rem >> 8, h = rem & 255;        // W2T[t][o][h] = W2[t][h][o]
    W2T[i] = f2bf(W2[(t << 15) + h * 128 + o]);
  }
}

__global__ __launch_bounds__(256) void k_hist(const int* __restrict__ NT, int n,
                                              int* __restrict__ meta) {
  __shared__ int c[NTYPES];
  if (threadIdx.x < NTYPES) c[threadIdx.x] = 0;
  __syncthreads();
  int i = blockIdx.x * 256 + threadIdx.x;
  if (i < n) atomicAdd(&c[NT[i]], 1);
  __syncthreads();
  if (threadIdx.x < NTYPES && c[threadIdx.x] > 0)
    atomicAdd(&meta[threadIdx.x], c[threadIdx.x]);
}

__global__ void k_prefix(int* meta) {
  if (threadIdx.x == 0) {
    int b = 0;
    meta[8] = 0;
    for (int t = 0; t < NTYPES; ++t) {
      b += (meta[t] + 63) & ~63;           // pad each segment to 64
      meta[9 + t] = b;
    }
  }
}

__global__ __launch_bounds__(256) void k_scatter(const int* __restrict__ NT, int n,
                                                 int* __restrict__ meta,
                                                 int* __restrict__ perm) {
  __shared__ int cnt[NTYPES];
  __shared__ int cbase[NTYPES];
  if (threadIdx.x < NTYPES) cnt[threadIdx.x] = 0;
  __syncthreads();
  int i = blockIdx.x * 256 + threadIdx.x;
  int t = 0, r = 0;
  bool valid = (i < n);
  if (valid) { t = NT[i]; r = atomicAdd(&cnt[t], 1); }
  __syncthreads();
  if (threadIdx.x < NTYPES)
    cbase[threadIdx.x] = atomicAdd(&meta[4 + threadIdx.x], cnt[threadIdx.x]);
  __syncthreads();
  if (valid) perm[meta[8 + t] + cbase[t] + r] = i;
}

// Fused per-type MLP over one 64-node type-uniform tile.
// layer1: h[64,256] = relu(x[64,128] @ W1[t]) ; layer2: out[64,128] = h @ W2[t]
__global__ __launch_bounds__(256) void k_mlp(
    const float* __restrict__ X, const int* __restrict__ perm,
    const int* __restrict__ meta,
    const unsigned short* __restrict__ W1T, const unsigned short* __restrict__ W2T,
    const float* __restrict__ B1, const float* __restrict__ B2,
    float* __restrict__ OUT) {
  __shared__ __align__(16) unsigned char x_lds[64 * 256];   // 64 rows x 128 bf16
  __shared__ __align__(16) unsigned char h_lds[64 * 512];   // 64 rows x 256 bf16
  __shared__ int s_rowid[64];

  const int tid = threadIdx.x;
  const int tile_start = blockIdx.x * 64;
  const int pb4 = meta[12];
  if (tile_start >= pb4) return;
  int t = 0;
  if (tile_start >= meta[9])  t = 1;
  if (tile_start >= meta[10]) t = 2;
  if (tile_start >= meta[11]) t = 3;

  if (tid < 64) s_rowid[tid] = perm[tile_start + tid];
  __syncthreads();

  // ---- stage x tile (f32 -> bf16, XOR-swizzled rows: byte ^= (row&7)<<4) ----
  {
    const int rr = tid >> 5;            // 0..7
    const int c4 = (tid & 31) * 4;      // f32 column
    #pragma unroll
    for (int p = 0; p < 8; ++p) {
      int r = p * 8 + rr;
      int rid = s_rowid[r];
      float4 v = make_float4(0.f, 0.f, 0.f, 0.f);
      if (rid >= 0) v = *(const float4*)(X + (size_t)rid * 128 + c4);
      ushort4 u;
      u.x = f2bf(v.x); u.y = f2bf(v.y); u.z = f2bf(v.z); u.w = f2bf(v.w);
      int byte = (r * 256 + c4 * 2) ^ ((r & 7) << 4);
      *(ushort4*)(x_lds + byte) = u;
    }
  }
  __syncthreads();

  const int l  = tid & 63;
  const int w  = tid >> 6;    // wave 0..3
  const int lo = l & 15;
  const int hi = l >> 4;

  // ---- layer 1: wave w owns hidden cols [w*64, w*64+64) ----
  f32x4 acc[4][4];
  #pragma unroll
  for (int m = 0; m < 4; ++m)
    #pragma unroll
    for (int n = 0; n < 4; ++n) acc[m][n] = (f32x4){0.f, 0.f, 0.f, 0.f};

  const int c0 = w * 64;
  const unsigned short* w1t = W1T + (t << 15);
  #pragma unroll
  for (int ks = 0; ks < 4; ++ks) {
    const int k8 = ks * 32 + hi * 8;
    short8 a[4];
    #pragma unroll
    for (int m = 0; m < 4; ++m) {
      int row = m * 16 + lo;
      int byte = (row * 256 + k8 * 2) ^ ((row & 7) << 4);
      a[m] = *(const short8*)(x_lds + byte);
    }
    short8 b[4];
    #pragma unroll
    for (int n = 0; n < 4; ++n) {
      int col = c0 + n * 16 + lo;
      b[n] = *(const short8*)(w1t + col * 128 + k8);
    }
    #pragma unroll
    for (int m = 0; m < 4; ++m)
      #pragma unroll
      for (int n = 0; n < 4; ++n)
        acc[m][n] = __builtin_amdgcn_mfma_f32_16x16x32_bf16(a[m], b[n], acc[m][n], 0, 0, 0);
  }

  // bias + relu + h -> LDS (bf16, swizzled)
  #pragma unroll
  for (int n = 0; n < 4; ++n) {
    int col = c0 + n * 16 + lo;
    float bias = B1[t * 256 + col];
    #pragma unroll
    for (int m = 0; m < 4; ++m) {
      #pragma unroll
      for (int r = 0; r < 4; ++r) {
        int row = m * 16 + hi * 4 + r;
        float v2 = acc[m][n][r] + bias;
        v2 = fmaxf(v2, 0.f);
        int byte = (row * 512 + col * 2) ^ ((row & 7) << 4);
        *(unsigned short*)(h_lds + byte) = f2bf(v2);
      }
    }
  }
  __syncthreads();

  // ---- layer 2: wave w owns out cols [w*32, w*32+32) ----
  f32x4 acc2[4][2];
  #pragma unroll
  for (int m = 0; m < 4; ++m)
    #pragma unroll
    for (int n = 0; n < 2; ++n) acc2[m][n] = (f32x4){0.f, 0.f, 0.f, 0.f};

  const int o0 = w * 32;
  const unsigned short* w2t = W2T + (t << 15);
  #pragma unroll
  for (int ks = 0; ks < 8; ++ks) {
    const int k8 = ks * 32 + hi * 8;
    short8 a[4];
    #pragma unroll
    for (int m = 0; m < 4; ++m) {
      int row = m * 16 + lo;
      int byte = (row * 512 + k8 * 2) ^ ((row & 7) << 4);
      a[m] = *(const short8*)(h_lds + byte);
    }
    short8 b[2];
    #pragma unroll
    for (int n = 0; n < 2; ++n) {
      int col = o0 + n * 16 + lo;
      b[n] = *(const short8*)(w2t + col * 256 + k8);
    }
    #pragma unroll
    for (int m = 0; m < 4; ++m)
      #pragma unroll
      for (int n = 0; n < 2; ++n)
        acc2[m][n] = __builtin_amdgcn_mfma_f32_16x16x32_bf16(a[m], b[n], acc2[m][n], 0, 0, 0);
  }

  // epilogue: bias + scatter-store f32
  #pragma unroll
  for (int n = 0; n < 2; ++n) {
    int col = o0 + n * 16 + lo;
    float bias = B2[t * 128 + col];
    #pragma unroll
    for (int m = 0; m < 4; ++m) {
      #pragma unroll
      for (int r = 0; r < 4; ++r) {
        int row = m * 16 + hi * 4 + r;
        int rid = s_rowid[row];
        if (rid >= 0) OUT[(size_t)rid * 128 + col] = acc2[m][n][r] + bias;
      }
    }
  }
}

extern "C" void kernel_launch(void* const* d_in, const int* in_sizes, int n_in,
                              void* d_out, int out_size, void* d_ws, size_t ws_size,
                              hipStream_t stream) {
  const float* X  = (const float*)d_in[0];
  const int*   NT = (const int*)d_in[1];
  const float* W1 = (const float*)d_in[2];
  const float* B1 = (const float*)d_in[3];
  const float* W2 = (const float*)d_in[4];
  const float* B2 = (const float*)d_in[5];
  float* OUT = (float*)d_out;
  const int n = in_sizes[1];

  char* ws = (char*)d_ws;
  int* meta = (int*)ws;                                   // counts/cursors/bases
  int* perm = (int*)(ws + 1024);
  unsigned short* W1T = (unsigned short*)(ws + 402432);
  unsigned short* W2T = (unsigned short*)(ws + 664576);

  const int ntiles = (n + 63) / 64 + NTYPES;              // worst-case padded tiles

  hipMemsetAsync(ws, 0, 64, stream);                      // counts + cursors = 0
  hipMemsetAsync(perm, 0xFF, (size_t)ntiles * 64 * sizeof(int), stream);  // perm = -1

  k_prep<<<512, 256, 0, stream>>>(W1, W2, W1T, W2T);
  const int nb = (n + 255) / 256;
  k_hist<<<nb, 256, 0, stream>>>(NT, n, meta);
  k_prefix<<<1, 64, 0, stream>>>(meta);
  k_scatter<<<nb, 256, 0, stream>>>(NT, n, meta, perm);
  k_mlp<<<ntiles, 256, 0, stream>>>(X, perm, meta, W1T, W2T, B1, B2, OUT);
}